// Round 18
// baseline (142.384 us; speedup 1.0000x reference)
//
#include <hip/hip_runtime.h>
#include <hip/hip_cooperative_groups.h>
#include <cstddef>
#include <cstdint>

namespace cg = cooperative_groups;

#define N_NODES 50000
#define N_EDGES 800000
#define D 128
#define BN_EPS 1e-5f

// Radix binning: bucket = dst >> 6 (64 nodes/bucket)
#define NBUCKET 782                  // 782*64 = 50048 >= 50000
#define BCAP 1536                    // per-bucket claim capacity (mean 1023 + 16 sigma)
#define PART_BLOCKS 256
#define PART_CHUNK 3125              // 256 * 3125 = 800000 exact
#define SLOTS 48                     // slots per node (Poisson(16): P(>=49) ~ 1e-11)
#define SLOTS_P 50                   // LDS slot stride (25 coprime 32 -> conflict-free)
#define GEMM_CHUNKS 1563             // ceil(50000/32)
#define GEMM_GRID   512
#define FEAT_V8     (N_NODES * D / 8)   // 800,000 octet jobs
#define SLICE_V8    (N_NODES * 4)       // 200,000 octets per column-quarter slice
#define W_V8        (D * D / 8)         // 2,048
#define CAST_BLOCKS ((FEAT_V8 + W_V8 + 255) / 256)   // 3133
#define ZERO_V4     3192                // int4s covering stats+gcur (51,072 B)

typedef __attribute__((ext_vector_type(8))) short short8_t;        // 8 x bf16 (mfma operand)
typedef __attribute__((ext_vector_type(8))) unsigned short u16x8;  // 8 x u16 storage
typedef __attribute__((ext_vector_type(4))) float f32x4;
typedef __attribute__((ext_vector_type(4))) int i32x4;

// ---------------- ws layout (bytes; ws = 256 MiB) ----------------
// stats      : 2 x float[128]     @ 0           (1,024)
// gcur       : int[782*16] padded @ 1,024       (50,048)
// wb (bf16 W): u16[16384]         @ 51,072      (32,768)
// claims     : u32[782*1536]      @ 83,840      (4,804,608)  [bucket-sorted]
// hb sliced  : u16[4][50000*32]   @ 4,888,448   (12,800,000) [bf16 agg, k-sliced]
// h2 (bf16 h): u16[50000*128]     @ 17,688,448  (12,800,000) [row-major]
// fb sliced  : u16[4][50000*32]   @ 30,488,448  (12,800,000)   total ~43 MB
#define WS_STAT_OFF    0
#define WS_GCUR_OFF    1024
#define WS_WB_OFF      51072
#define WS_CLAIM_OFF   83840
#define WS_HB_OFF      4888448
#define WS_H2_OFF      17688448
#define WS_FB_OFF      30488448

static __device__ __forceinline__ unsigned short f2bf(float x) {
    unsigned u = __float_as_uint(x);
    unsigned r = (u + 0x7fffu + ((u >> 16) & 1u)) >> 16;   // RNE
    return (unsigned short)r;
}
static __device__ __forceinline__ float bf2f(unsigned short v) {
    return __uint_as_float(((unsigned)v) << 16);
}

// Zero gcur + stats (51 KB). Own kernel: runtime fillBuffer costs ~40 us.
__global__ __launch_bounds__(256) void prezero_k(i32x4* __restrict__ zws) {
    int i = blockIdx.x * 256 + threadIdx.x;
    if (i < ZERO_V4) zws[i] = (i32x4){0, 0, 0, 0};
}

// Fused cast + partition (block-role split).
// Blocks [0,256): partition -> globally bucket-sorted claims via one padded
//   global atomic per (block,bucket); gcur[b*16] ends as bucket edge count.
// Blocks [256,...): cast feature to column-sliced bf16 fb + W to wb.
__global__ __launch_bounds__(256) void castpart_k(const float* __restrict__ feat,
                                                  const float* __restrict__ W,
                                                  u16x8* __restrict__ fb,
                                                  u16x8* __restrict__ wb,
                                                  const int* __restrict__ src,
                                                  const int* __restrict__ dst,
                                                  int* __restrict__ gcur,
                                                  unsigned* __restrict__ claims) {
    __shared__ unsigned pk[PART_CHUNK];      // 12,500 B
    __shared__ int hist[NBUCKET];            // 3,128 B
    __shared__ int base_l[NBUCKET];          // 3,128 B
    const int t = threadIdx.x;

    if (blockIdx.x < PART_BLOCKS) {
        const int base = blockIdx.x * PART_CHUNK;

        for (int b = t; b < NBUCKET; b += 256) hist[b] = 0;
        __syncthreads();

        for (int i = t; i < PART_CHUNK; i += 256) {
            int s = __builtin_nontemporal_load(src + base + i);
            int d = __builtin_nontemporal_load(dst + base + i);
            pk[i] = ((unsigned)s << 16) | (unsigned)d;
            atomicAdd(&hist[d >> 6], 1);
        }
        __syncthreads();

        for (int b = t; b < NBUCKET; b += 256) {
            int h = hist[b];
            base_l[b] = h ? atomicAdd(gcur + b * 16, h) : 0;
            hist[b] = 0;                      // reuse as running offset
        }
        __syncthreads();

        for (int i = t; i < PART_CHUNK; i += 256) {
            unsigned u = pk[i];
            int bkt = (int)(u & 0xffffu) >> 6;
            int k = atomicAdd(&hist[bkt], 1);
            int pos = base_l[bkt] + k;
            if (pos < BCAP) claims[bkt * BCAP + pos] = u;
        }
    } else {
        int i = (blockIdx.x - PART_BLOCKS) * 256 + t;
        if (i < FEAT_V8) {
            // job i -> slice q, node n, octet oc; fb[i] IS the sliced address
            int q  = i / SLICE_V8;                // 0..3
            int r  = i - q * SLICE_V8;
            int n  = r >> 2, oc = r & 3;
            const f32x4* fp = reinterpret_cast<const f32x4*>(feat + n * D + q * 32 + oc * 8);
            f32x4 x0 = __builtin_nontemporal_load(fp);
            f32x4 x1 = __builtin_nontemporal_load(fp + 1);
            u16x8 o;
            o[0] = f2bf(x0.x); o[1] = f2bf(x0.y); o[2] = f2bf(x0.z); o[3] = f2bf(x0.w);
            o[4] = f2bf(x1.x); o[5] = f2bf(x1.y); o[6] = f2bf(x1.z); o[7] = f2bf(x1.w);
            __builtin_nontemporal_store(o, fb + i);
        } else if (i < FEAT_V8 + W_V8) {
            int j = i - FEAT_V8;
            const f32x4* fp = reinterpret_cast<const f32x4*>(W) + j * 2;
            f32x4 x0 = __builtin_nontemporal_load(fp);
            f32x4 x1 = __builtin_nontemporal_load(fp + 1);
            u16x8 o;
            o[0] = f2bf(x0.x); o[1] = f2bf(x0.y); o[2] = f2bf(x0.z); o[3] = f2bf(x0.w);
            o[4] = f2bf(x1.x); o[5] = f2bf(x1.y); o[6] = f2bf(x1.z); o[7] = f2bf(x1.w);
            __builtin_nontemporal_store(o, wb + j);
        }
    }
}

// Bin + gather, column-quarter sliced. Block = (bucket b, quarter q).
// Bin: bucket's claims are contiguous -> coalesced sweeps into LDS slot lists.
// Gather: thread = (node, octet); 4 lanes of a node read the same 64 B fb
// line; fb slice (3.2 MB) stays in one XCD's L2 (q = blockIdx&3 round-robin).
// hb output is SLICED like fb -> fully coalesced contiguous write.
__global__ __launch_bounds__(256) void bingather_k(const int* __restrict__ gcur,
                                                   const unsigned* __restrict__ claims,
                                                   const u16x8* __restrict__ fb,
                                                   u16x8* __restrict__ hb) {
    __shared__ unsigned short ebl[64 * SLOTS_P];   // 6,400 B
    __shared__ int lcnt[64];
    const int t = threadIdx.x;
    const int b = blockIdx.x >> 2;
    const int q = blockIdx.x & 3;
    const u16x8* fbq = fb + (size_t)q * SLICE_V8;

    if (t < 64) lcnt[t] = 0;
    __syncthreads();

    const int n = min(gcur[b * 16], BCAP);
    const unsigned* cp = claims + b * BCAP;
    for (int i = t; i < n; i += 256) {
        unsigned u = cp[i];
        int dl = (int)(u & 63u);
        int k = atomicAdd(&lcnt[dl], 1);
        if (k < SLOTS) ebl[dl * SLOTS_P + k] = (unsigned short)(u >> 16);
    }
    __syncthreads();

    const int nl = t >> 2;               // node-local 0..63
    const int oc = t & 3;                // octet within quarter
    const int node = (b << 6) + nl;
    const int deg = lcnt[nl];
    const int nd  = min(deg, SLOTS);
    const unsigned short* slots = ebl + nl * SLOTS_P;

    float a[8];
#pragma unroll
    for (int i = 0; i < 8; ++i) a[i] = 0.f;

    int e = 0;
    for (; e + 4 <= nd; e += 4) {
        int s0 = slots[e],     s1 = slots[e + 1];
        int s2 = slots[e + 2], s3 = slots[e + 3];
        u16x8 v0 = fbq[s0 * 4 + oc];
        u16x8 v1 = fbq[s1 * 4 + oc];
        u16x8 v2 = fbq[s2 * 4 + oc];
        u16x8 v3 = fbq[s3 * 4 + oc];
#pragma unroll
        for (int i = 0; i < 8; ++i) a[i] += (bf2f(v0[i]) + bf2f(v1[i])) +
                                            (bf2f(v2[i]) + bf2f(v3[i]));
    }
    for (; e < nd; ++e) {
        u16x8 v0 = fbq[(int)slots[e] * 4 + oc];
#pragma unroll
        for (int i = 0; i < 8; ++i) a[i] += bf2f(v0[i]);
    }

    if (node < N_NODES) {
        float inv = (deg > 0) ? 1.f / (float)deg : 0.f;
        u16x8 o;
#pragma unroll
        for (int i = 0; i < 8; ++i) o[i] = f2bf(a[i] * inv);
        hb[(size_t)q * SLICE_V8 + node * 4 + oc] = o;   // sliced: coalesced
    }
}

// Cooperative fused GEMM + BN epilogue.
// Phase 1: h2(bf16) = hb @ W^T + b, atomic column stats.
// grid.sync()
// Phase 2: each block re-reads ITS OWN h2 rows (L2-warm on its XCD) and
// writes out = feat + relu((h2-mu)*rstd*gamma + beta). BN scale/shift is
// computed once per thread (colb invariant across its chunks).
__global__ __launch_bounds__(256) void gemmepi_k(const u16x8* __restrict__ hb,
                                                 const u16x8* __restrict__ wb,
                                                 const float* __restrict__ bias,
                                                 unsigned short* __restrict__ h2,
                                                 float* __restrict__ colsum,
                                                 float* __restrict__ colsumsq,
                                                 const float* __restrict__ gamma,
                                                 const float* __restrict__ beta,
                                                 const float* __restrict__ feat,
                                                 float* __restrict__ out) {
    const int wave = threadIdx.x >> 6;
    const int lane = threadIdx.x & 63;
    const int wm = wave >> 1, wn = wave & 1;
    const int l15 = lane & 15, l4 = lane >> 4;

    short8_t bf[4][4];
#pragma unroll
    for (int t = 0; t < 4; ++t) {
        const int col = wn * 64 + t * 16 + l15;
#pragma unroll
        for (int s = 0; s < 4; ++s) {
            u16x8 w = wb[col * 16 + s * 4 + l4];
            short8_t b8;
#pragma unroll
            for (int i = 0; i < 8; ++i) b8[i] = (short)w[i];
            bf[t][s] = b8;
        }
    }
    float bc[4];
#pragma unroll
    for (int t = 0; t < 4; ++t) bc[t] = bias[wn * 64 + t * 16 + l15];

    float s1[4] = {0.f, 0.f, 0.f, 0.f};
    float s2[4] = {0.f, 0.f, 0.f, 0.f};

    for (int chunk = blockIdx.x; chunk < GEMM_CHUNKS; chunk += gridDim.x) {
        const int rbase = chunk * 32 + wm * 16;
        const int arow = min(rbase + l15, N_NODES - 1);
        short8_t af[4];
#pragma unroll
        for (int s = 0; s < 4; ++s) {
            u16x8 hv8 = hb[(size_t)s * SLICE_V8 + arow * 4 + l4];
            short8_t t8;
#pragma unroll
            for (int i = 0; i < 8; ++i) t8[i] = (short)hv8[i];
            af[s] = t8;
        }

        f32x4 acc[4];
#pragma unroll
        for (int t = 0; t < 4; ++t) acc[t] = (f32x4){0.f, 0.f, 0.f, 0.f};

#pragma unroll
        for (int s = 0; s < 4; ++s)
#pragma unroll
            for (int t = 0; t < 4; ++t)
                acc[t] = __builtin_amdgcn_mfma_f32_16x16x32_bf16(af[s], bf[t][s],
                                                                 acc[t], 0, 0, 0);

        const int orow0 = rbase + l4 * 4;
#pragma unroll
        for (int t = 0; t < 4; ++t) {
            const int col = wn * 64 + t * 16 + l15;
#pragma unroll
            for (int r = 0; r < 4; ++r) {
                const int row = orow0 + r;
                if (row < N_NODES) {
                    float hv = acc[t][r] + bc[t];
                    h2[(size_t)row * D + col] = f2bf(hv);
                    s1[t] += hv;
                    s2[t] += hv * hv;
                }
            }
        }
    }

#pragma unroll
    for (int t = 0; t < 4; ++t) {
        s1[t] += __shfl_xor(s1[t], 16); s1[t] += __shfl_xor(s1[t], 32);
        s2[t] += __shfl_xor(s2[t], 16); s2[t] += __shfl_xor(s2[t], 32);
    }
    if (lane < 16) {
#pragma unroll
        for (int t = 0; t < 4; ++t) {
            int col = wn * 64 + t * 16 + lane;
            atomicAdd(colsum + col, s1[t]);
            atomicAdd(colsumsq + col, s2[t]);
        }
    }

    cg::this_grid().sync();

    // ---- epilogue phase ----
    const float inv_n = 1.0f / N_NODES;
    const int colb = (threadIdx.x & 15) * 8;     // invariant across reps/chunks
    float av[8], bv[8];
#pragma unroll
    for (int i = 0; i < 8; ++i) {
        int c = colb + i;
        float mu  = colsum[c] * inv_n;
        float var = colsumsq[c] * inv_n - mu * mu;
        float a   = gamma[c] * rsqrtf(var + BN_EPS);
        av[i] = a;
        bv[i] = beta[c] - mu * a;
    }
    const u16x8* h2v = reinterpret_cast<const u16x8*>(h2);

    for (int chunk = blockIdx.x; chunk < GEMM_CHUNKS; chunk += gridDim.x) {
        const int rbase = chunk * 32;
#pragma unroll
        for (int rep = 0; rep < 2; ++rep) {
            int j = rep * 256 + threadIdx.x;     // 0..511: (row-local j>>4, octet j&15)
            int row = rbase + (j >> 4);
            if (row < N_NODES) {
                int idx = row * 16 + (j & 15);   // octet index
                u16x8 hv8 = h2v[idx];
                const float4* fp = reinterpret_cast<const float4*>(feat) + idx * 2;
                float4 fv0 = fp[0], fv1 = fp[1];
                float4 o0, o1;
#pragma unroll
                for (int i = 0; i < 8; ++i) {
                    float hv = bf2f(hv8[i]);
                    float fv = (i < 4) ? (&fv0.x)[i] : (&fv1.x)[i - 4];
                    float ov = fv + fmaxf(hv * av[i] + bv[i], 0.f);
                    if (i < 4) (&o0.x)[i] = ov; else (&o1.x)[i - 4] = ov;
                }
                float4* op = reinterpret_cast<float4*>(out) + idx * 2;
                op[0] = o0;
                op[1] = o1;
            }
        }
    }
}

extern "C" void kernel_launch(void* const* d_in, const int* in_sizes, int n_in,
                              void* d_out, int out_size, void* d_ws, size_t ws_size,
                              hipStream_t stream) {
    const float* feature = (const float*)d_in[0];
    const float* W       = (const float*)d_in[1];
    const float* b       = (const float*)d_in[2];
    const float* gamma   = (const float*)d_in[3];
    const float* beta    = (const float*)d_in[4];
    const int*   src     = (const int*)d_in[5];
    const int*   dst     = (const int*)d_in[6];
    float* out = (float*)d_out;

    char* ws = (char*)d_ws;
    float*          colsum   = (float*)(ws + WS_STAT_OFF);
    float*          colsumsq = colsum + 128;
    int*            gcur     = (int*)(ws + WS_GCUR_OFF);
    u16x8*          wb       = (u16x8*)(ws + WS_WB_OFF);
    unsigned*       claims   = (unsigned*)(ws + WS_CLAIM_OFF);
    u16x8*          hb       = (u16x8*)(ws + WS_HB_OFF);
    unsigned short* h2       = (unsigned short*)(ws + WS_H2_OFF);
    u16x8*          fb       = (u16x8*)(ws + WS_FB_OFF);

    prezero_k<<<13, 256, 0, stream>>>((i32x4*)ws);
    castpart_k<<<PART_BLOCKS + CAST_BLOCKS, 256, 0, stream>>>(
        feature, W, fb, wb, src, dst, gcur, claims);
    bingather_k<<<NBUCKET * 4, 256, 0, stream>>>(gcur, claims, fb, hb);

    const u16x8*          hb_p   = hb;
    const u16x8*          wb_p   = wb;
    const float*          b_p    = b;
    unsigned short*       h2_p   = h2;
    float*                cs_p   = colsum;
    float*                cq_p   = colsumsq;
    const float*          g_p    = gamma;
    const float*          bt_p   = beta;
    const float*          f_p    = feature;
    float*                out_p  = out;
    void* kargs[] = {(void*)&hb_p, (void*)&wb_p, (void*)&b_p, (void*)&h2_p,
                     (void*)&cs_p, (void*)&cq_p, (void*)&g_p, (void*)&bt_p,
                     (void*)&f_p, (void*)&out_p};
    hipLaunchCooperativeKernel((void*)gemmepi_k, dim3(GEMM_GRID), dim3(256),
                               kargs, 0, stream);
}

// Round 19
// 133.588 us; speedup vs baseline: 1.0658x; 1.0658x over previous
//
#include <hip/hip_runtime.h>
#include <cstddef>
#include <cstdint>

#define N_NODES 50000
#define N_EDGES 800000
#define D 128
#define BN_EPS 1e-5f

// Radix binning: bucket = dst >> 6 (64 nodes/bucket)
#define NBUCKET 782                  // 782*64 = 50048 >= 50000
#define BCAP 1536                    // per-bucket claim capacity (mean 1023 + 16 sigma)
#define PART_BLOCKS 256
#define PART_CHUNK 3125              // 256 * 3125 = 800000 exact
#define SLOTS 48                     // slots per node (Poisson(16): P(>=49) ~ 1e-11)
#define SLOTS_P 50                   // LDS slot stride (25 coprime 32 -> conflict-free)
#define GEMM_CHUNKS 1563             // ceil(50000/32)
#define GEMM_GRID   1024
#define FEAT_V8     (N_NODES * D / 8)   // 800,000 octet jobs
#define SLICE_V8    (N_NODES * 4)       // 200,000 octets per column-quarter slice
#define W_V8        (D * D / 8)         // 2,048
#define CAST_BLOCKS ((FEAT_V8 + W_V8 + 255) / 256)   // 3133
#define ZERO_V4     3192                // int4s covering stats+gcur (51,072 B)

typedef __attribute__((ext_vector_type(8))) short short8_t;        // 8 x bf16 (mfma operand)
typedef __attribute__((ext_vector_type(8))) unsigned short u16x8;  // 8 x u16 storage
typedef __attribute__((ext_vector_type(4))) float f32x4;
typedef __attribute__((ext_vector_type(4))) int i32x4;

// ---------------- ws layout (bytes; ws = 256 MiB) ----------------
// stats      : 2 x float[128]     @ 0           (1,024)
// gcur       : int[782*16] padded @ 1,024       (50,048)
// wb (bf16 W): u16[16384]         @ 51,072      (32,768)
// claims     : u32[782*1536]      @ 83,840      (4,804,608)  [bucket-sorted]
// hb sliced  : u16[4][50000*32]   @ 4,888,448   (12,800,000) [bf16 agg, k-sliced]
// h2 (bf16 h): u16[50000*128]     @ 17,688,448  (12,800,000) [row-major]
// fb sliced  : u16[4][50000*32]   @ 30,488,448  (12,800,000)   total ~43 MB
#define WS_STAT_OFF    0
#define WS_GCUR_OFF    1024
#define WS_WB_OFF      51072
#define WS_CLAIM_OFF   83840
#define WS_HB_OFF      4888448
#define WS_H2_OFF      17688448
#define WS_FB_OFF      30488448

static __device__ __forceinline__ unsigned short f2bf(float x) {
    unsigned u = __float_as_uint(x);
    unsigned r = (u + 0x7fffu + ((u >> 16) & 1u)) >> 16;   // RNE
    return (unsigned short)r;
}
static __device__ __forceinline__ float bf2f(unsigned short v) {
    return __uint_as_float(((unsigned)v) << 16);
}

// Zero gcur + stats (51 KB). Own kernel: runtime fillBuffer costs ~40 us.
__global__ __launch_bounds__(256) void prezero_k(i32x4* __restrict__ zws) {
    int i = blockIdx.x * 256 + threadIdx.x;
    if (i < ZERO_V4) zws[i] = (i32x4){0, 0, 0, 0};
}

// Fused cast + partition (block-role split).
// Blocks [0,256): partition -> globally bucket-sorted claims via one padded
//   global atomic per (block,bucket); gcur[b*16] ends as bucket edge count.
// Blocks [256,...): cast feature to column-sliced bf16 fb + W to wb.
__global__ __launch_bounds__(256) void castpart_k(const float* __restrict__ feat,
                                                  const float* __restrict__ W,
                                                  u16x8* __restrict__ fb,
                                                  u16x8* __restrict__ wb,
                                                  const int* __restrict__ src,
                                                  const int* __restrict__ dst,
                                                  int* __restrict__ gcur,
                                                  unsigned* __restrict__ claims) {
    __shared__ unsigned pk[PART_CHUNK];      // 12,500 B
    __shared__ int hist[NBUCKET];            // 3,128 B
    __shared__ int base_l[NBUCKET];          // 3,128 B
    const int t = threadIdx.x;

    if (blockIdx.x < PART_BLOCKS) {
        const int base = blockIdx.x * PART_CHUNK;

        for (int b = t; b < NBUCKET; b += 256) hist[b] = 0;
        __syncthreads();

        for (int i = t; i < PART_CHUNK; i += 256) {
            int s = __builtin_nontemporal_load(src + base + i);
            int d = __builtin_nontemporal_load(dst + base + i);
            pk[i] = ((unsigned)s << 16) | (unsigned)d;
            atomicAdd(&hist[d >> 6], 1);
        }
        __syncthreads();

        for (int b = t; b < NBUCKET; b += 256) {
            int h = hist[b];
            base_l[b] = h ? atomicAdd(gcur + b * 16, h) : 0;
            hist[b] = 0;                      // reuse as running offset
        }
        __syncthreads();

        for (int i = t; i < PART_CHUNK; i += 256) {
            unsigned u = pk[i];
            int bkt = (int)(u & 0xffffu) >> 6;
            int k = atomicAdd(&hist[bkt], 1);
            int pos = base_l[bkt] + k;
            if (pos < BCAP) claims[bkt * BCAP + pos] = u;
        }
    } else {
        int i = (blockIdx.x - PART_BLOCKS) * 256 + t;
        if (i < FEAT_V8) {
            // job i -> slice q, node n, octet oc; fb[i] IS the sliced address
            int q  = i / SLICE_V8;                // 0..3
            int r  = i - q * SLICE_V8;
            int n  = r >> 2, oc = r & 3;
            const f32x4* fp = reinterpret_cast<const f32x4*>(feat + n * D + q * 32 + oc * 8);
            f32x4 x0 = __builtin_nontemporal_load(fp);
            f32x4 x1 = __builtin_nontemporal_load(fp + 1);
            u16x8 o;
            o[0] = f2bf(x0.x); o[1] = f2bf(x0.y); o[2] = f2bf(x0.z); o[3] = f2bf(x0.w);
            o[4] = f2bf(x1.x); o[5] = f2bf(x1.y); o[6] = f2bf(x1.z); o[7] = f2bf(x1.w);
            __builtin_nontemporal_store(o, fb + i);
        } else if (i < FEAT_V8 + W_V8) {
            int j = i - FEAT_V8;
            const f32x4* fp = reinterpret_cast<const f32x4*>(W) + j * 2;
            f32x4 x0 = __builtin_nontemporal_load(fp);
            f32x4 x1 = __builtin_nontemporal_load(fp + 1);
            u16x8 o;
            o[0] = f2bf(x0.x); o[1] = f2bf(x0.y); o[2] = f2bf(x0.z); o[3] = f2bf(x0.w);
            o[4] = f2bf(x1.x); o[5] = f2bf(x1.y); o[6] = f2bf(x1.z); o[7] = f2bf(x1.w);
            __builtin_nontemporal_store(o, wb + j);
        }
    }
}

// Bin + gather, column-quarter sliced. Block = (bucket b, quarter q).
// Bin: bucket's claims are contiguous -> coalesced sweeps into LDS slot lists.
// Gather: thread = (node, octet); 4 lanes of a node read the same 64 B fb
// line; fb slice (3.2 MB) stays in one XCD's L2 (q = blockIdx&3 round-robin).
// hb output is SLICED like fb -> fully coalesced contiguous write.
__global__ __launch_bounds__(256) void bingather_k(const int* __restrict__ gcur,
                                                   const unsigned* __restrict__ claims,
                                                   const u16x8* __restrict__ fb,
                                                   u16x8* __restrict__ hb) {
    __shared__ unsigned short ebl[64 * SLOTS_P];   // 6,400 B
    __shared__ int lcnt[64];
    const int t = threadIdx.x;
    const int b = blockIdx.x >> 2;
    const int q = blockIdx.x & 3;
    const u16x8* fbq = fb + (size_t)q * SLICE_V8;

    if (t < 64) lcnt[t] = 0;
    __syncthreads();

    const int n = min(gcur[b * 16], BCAP);
    const unsigned* cp = claims + b * BCAP;
    for (int i = t; i < n; i += 256) {
        unsigned u = cp[i];
        int dl = (int)(u & 63u);
        int k = atomicAdd(&lcnt[dl], 1);
        if (k < SLOTS) ebl[dl * SLOTS_P + k] = (unsigned short)(u >> 16);
    }
    __syncthreads();

    const int nl = t >> 2;               // node-local 0..63
    const int oc = t & 3;                // octet within quarter
    const int node = (b << 6) + nl;
    const int deg = lcnt[nl];
    const int nd  = min(deg, SLOTS);
    const unsigned short* slots = ebl + nl * SLOTS_P;

    float a[8];
#pragma unroll
    for (int i = 0; i < 8; ++i) a[i] = 0.f;

    int e = 0;
    for (; e + 8 <= nd; e += 8) {        // 8-edge unroll: more loads in flight
        int s0 = slots[e],     s1 = slots[e + 1];
        int s2 = slots[e + 2], s3 = slots[e + 3];
        int s4 = slots[e + 4], s5 = slots[e + 5];
        int s6 = slots[e + 6], s7 = slots[e + 7];
        u16x8 v0 = fbq[s0 * 4 + oc];
        u16x8 v1 = fbq[s1 * 4 + oc];
        u16x8 v2 = fbq[s2 * 4 + oc];
        u16x8 v3 = fbq[s3 * 4 + oc];
        u16x8 v4 = fbq[s4 * 4 + oc];
        u16x8 v5 = fbq[s5 * 4 + oc];
        u16x8 v6 = fbq[s6 * 4 + oc];
        u16x8 v7 = fbq[s7 * 4 + oc];
#pragma unroll
        for (int i = 0; i < 8; ++i)
            a[i] += ((bf2f(v0[i]) + bf2f(v1[i])) + (bf2f(v2[i]) + bf2f(v3[i]))) +
                    ((bf2f(v4[i]) + bf2f(v5[i])) + (bf2f(v6[i]) + bf2f(v7[i])));
    }
    for (; e < nd; ++e) {
        u16x8 v0 = fbq[(int)slots[e] * 4 + oc];
#pragma unroll
        for (int i = 0; i < 8; ++i) a[i] += bf2f(v0[i]);
    }

    if (node < N_NODES) {
        float inv = (deg > 0) ? 1.f / (float)deg : 0.f;
        u16x8 o;
#pragma unroll
        for (int i = 0; i < 8; ++i) o[i] = f2bf(a[i] * inv);
        hb[(size_t)q * SLICE_V8 + node * 4 + oc] = o;   // sliced: coalesced
    }
}

// MFMA GEMM: h2(bf16) = hb @ W^T + b + column stats (f32, pre-rounding).
// hb is k-sliced: af[s] comes from slice s. h2 write: per (wave,r) the 64
// cols x 2 B = 128 B contiguous.
__global__ __launch_bounds__(256) void gemm_mfma_k(const u16x8* __restrict__ hb,
                                                   const u16x8* __restrict__ wb,
                                                   const float* __restrict__ bias,
                                                   unsigned short* __restrict__ h2,
                                                   float* __restrict__ colsum,
                                                   float* __restrict__ colsumsq) {
    const int wave = threadIdx.x >> 6;
    const int lane = threadIdx.x & 63;
    const int wm = wave >> 1, wn = wave & 1;
    const int l15 = lane & 15, l4 = lane >> 4;

    short8_t bf[4][4];
#pragma unroll
    for (int t = 0; t < 4; ++t) {
        const int col = wn * 64 + t * 16 + l15;
#pragma unroll
        for (int s = 0; s < 4; ++s) {
            u16x8 w = wb[col * 16 + s * 4 + l4];
            short8_t b8;
#pragma unroll
            for (int i = 0; i < 8; ++i) b8[i] = (short)w[i];
            bf[t][s] = b8;
        }
    }
    float bc[4];
#pragma unroll
    for (int t = 0; t < 4; ++t) bc[t] = bias[wn * 64 + t * 16 + l15];

    float s1[4] = {0.f, 0.f, 0.f, 0.f};
    float s2[4] = {0.f, 0.f, 0.f, 0.f};

    for (int chunk = blockIdx.x; chunk < GEMM_CHUNKS; chunk += gridDim.x) {
        const int rbase = chunk * 32 + wm * 16;
        const int arow = min(rbase + l15, N_NODES - 1);
        short8_t af[4];
#pragma unroll
        for (int s = 0; s < 4; ++s) {
            u16x8 hv8 = hb[(size_t)s * SLICE_V8 + arow * 4 + l4];
            short8_t t8;
#pragma unroll
            for (int i = 0; i < 8; ++i) t8[i] = (short)hv8[i];
            af[s] = t8;
        }

        f32x4 acc[4];
#pragma unroll
        for (int t = 0; t < 4; ++t) acc[t] = (f32x4){0.f, 0.f, 0.f, 0.f};

#pragma unroll
        for (int s = 0; s < 4; ++s)
#pragma unroll
            for (int t = 0; t < 4; ++t)
                acc[t] = __builtin_amdgcn_mfma_f32_16x16x32_bf16(af[s], bf[t][s],
                                                                 acc[t], 0, 0, 0);

        const int orow0 = rbase + l4 * 4;
#pragma unroll
        for (int t = 0; t < 4; ++t) {
            const int col = wn * 64 + t * 16 + l15;
#pragma unroll
            for (int r = 0; r < 4; ++r) {
                const int row = orow0 + r;
                if (row < N_NODES) {
                    float hv = acc[t][r] + bc[t];
                    h2[(size_t)row * D + col] = f2bf(hv);
                    s1[t] += hv;
                    s2[t] += hv * hv;
                }
            }
        }
    }

#pragma unroll
    for (int t = 0; t < 4; ++t) {
        s1[t] += __shfl_xor(s1[t], 16); s1[t] += __shfl_xor(s1[t], 32);
        s2[t] += __shfl_xor(s2[t], 16); s2[t] += __shfl_xor(s2[t], 32);
    }
    if (lane < 16) {
#pragma unroll
        for (int t = 0; t < 4; ++t) {
            int col = wn * 64 + t * 16 + lane;
            atomicAdd(colsum + col, s1[t]);
            atomicAdd(colsumsq + col, s2[t]);
        }
    }
}

// out = feature + relu((h2 - mu) * rstd * gamma + beta). h2 is bf16 (16 B per
// 8 cols); feat/out are f32 (2 x float4 per thread).
__global__ __launch_bounds__(256) void epilogue_k(const u16x8* __restrict__ h2v,
                                                  const float* __restrict__ feat,
                                                  const float* __restrict__ colsum,
                                                  const float* __restrict__ colsumsq,
                                                  const float* __restrict__ gamma,
                                                  const float* __restrict__ beta,
                                                  float* __restrict__ out) {
    int idx = blockIdx.x * 256 + threadIdx.x;      // octet index, 800,000 total
    if (idx >= FEAT_V8) return;
    const int colb = (idx * 8) & 127;
    const float inv_n = 1.0f / N_NODES;

    u16x8 hv8 = h2v[idx];
    const float4* fp = reinterpret_cast<const float4*>(feat) + idx * 2;
    float4 fv0 = fp[0], fv1 = fp[1];
    float4 o0, o1;
#pragma unroll
    for (int i = 0; i < 8; ++i) {
        int c = colb + i;
        float mu  = colsum[c] * inv_n;
        float var = colsumsq[c] * inv_n - mu * mu;
        float a   = gamma[c] * rsqrtf(var + BN_EPS);
        float bb  = beta[c] - mu * a;
        float hv  = bf2f(hv8[i]);
        float fv  = (i < 4) ? (&fv0.x)[i] : (&fv1.x)[i - 4];
        float ov  = fv + fmaxf(hv * a + bb, 0.f);
        if (i < 4) (&o0.x)[i] = ov; else (&o1.x)[i - 4] = ov;
    }
    float4* op = reinterpret_cast<float4*>(out) + idx * 2;
    op[0] = o0;
    op[1] = o1;
}

extern "C" void kernel_launch(void* const* d_in, const int* in_sizes, int n_in,
                              void* d_out, int out_size, void* d_ws, size_t ws_size,
                              hipStream_t stream) {
    const float* feature = (const float*)d_in[0];
    const float* W       = (const float*)d_in[1];
    const float* b       = (const float*)d_in[2];
    const float* gamma   = (const float*)d_in[3];
    const float* beta    = (const float*)d_in[4];
    const int*   src     = (const int*)d_in[5];
    const int*   dst     = (const int*)d_in[6];
    float* out = (float*)d_out;

    char* ws = (char*)d_ws;
    float*          colsum   = (float*)(ws + WS_STAT_OFF);
    float*          colsumsq = colsum + 128;
    int*            gcur     = (int*)(ws + WS_GCUR_OFF);
    u16x8*          wb       = (u16x8*)(ws + WS_WB_OFF);
    unsigned*       claims   = (unsigned*)(ws + WS_CLAIM_OFF);
    u16x8*          hb       = (u16x8*)(ws + WS_HB_OFF);
    unsigned short* h2       = (unsigned short*)(ws + WS_H2_OFF);
    u16x8*          fb       = (u16x8*)(ws + WS_FB_OFF);

    prezero_k<<<13, 256, 0, stream>>>((i32x4*)ws);
    castpart_k<<<PART_BLOCKS + CAST_BLOCKS, 256, 0, stream>>>(
        feature, W, fb, wb, src, dst, gcur, claims);
    bingather_k<<<NBUCKET * 4, 256, 0, stream>>>(gcur, claims, fb, hb);
    gemm_mfma_k<<<GEMM_GRID, 256, 0, stream>>>(hb, wb, b, h2, colsum, colsumsq);
    epilogue_k<<<(FEAT_V8 + 255) / 256, 256, 0, stream>>>(
        (u16x8*)h2, feature, colsum, colsumsq, gamma, beta, out);
}

// Round 20
// 90.477 us; speedup vs baseline: 1.5737x; 1.4765x over previous
//
#include <hip/hip_runtime.h>
#include <cstddef>
#include <cstdint>

#define N_NODES 50000
#define N_EDGES 800000
#define D 128
#define BN_EPS 1e-5f

// Radix binning: bucket = dst >> 6 (64 nodes/bucket)
#define NBUCKET 782                  // 782*64 = 50048 >= 50000
#define BCAP 1536                    // per-bucket claim capacity (mean 1023 + 16 sigma)
#define PART_BLOCKS 256
#define PART_CHUNK 3125              // 256 * 3125 = 800000 exact
#define SLOTS 48                     // slots per node (Poisson(16): P(>=49) ~ 1e-11)
#define SLOTS_P 50                   // LDS slot stride (25 coprime 32 -> conflict-free)
#define GEMM_CHUNKS 1563             // ceil(50000/32)
#define GEMM_GRID   512
#define FEAT_V8     (N_NODES * D / 8)   // 800,000 octet jobs
#define SLICE_V8    (N_NODES * 4)       // 200,000 octets per column-quarter slice
#define W_V8        (D * D / 8)         // 2,048
#define CAST_BLOCKS ((FEAT_V8 + W_V8 + 255) / 256)   // 3133
#define ZERO_V4     3704                // int4s covering stats+stat8+gcur (59,264 B)

typedef __attribute__((ext_vector_type(8))) short short8_t;        // 8 x bf16 (mfma operand)
typedef __attribute__((ext_vector_type(8))) unsigned short u16x8;  // 8 x u16 storage
typedef __attribute__((ext_vector_type(4))) float f32x4;
typedef __attribute__((ext_vector_type(4))) int i32x4;

// ---------------- ws layout (bytes; ws = 256 MiB) ----------------
// stats      : 2 x float[128]     @ 0           (1,024)   [colsum, colsumsq]
// stat8      : 2 x float[8][128]  @ 1,024       (8,192)   [sharded partials]
// gcur       : int[782*16] padded @ 9,216       (50,048)
// wb (bf16 W): u16[16384]         @ 59,264      (32,768)
// claims     : u32[782*1536]      @ 92,032      (4,804,608)  [bucket-sorted]
// hb sliced  : u16[4][50000*32]   @ 4,896,640   (12,800,000) [bf16 agg, k-sliced]
// h2 (bf16 h): u16[50000*128]     @ 17,696,640  (12,800,000) [row-major]
// fb sliced  : u16[4][50000*32]   @ 30,496,640  (12,800,000)
#define WS_STAT_OFF    0
#define WS_STAT8_OFF   1024
#define WS_GCUR_OFF    9216
#define WS_WB_OFF      59264
#define WS_CLAIM_OFF   92032
#define WS_HB_OFF      4896640
#define WS_H2_OFF      17696640
#define WS_FB_OFF      30496640

static __device__ __forceinline__ unsigned short f2bf(float x) {
    unsigned u = __float_as_uint(x);
    unsigned r = (u + 0x7fffu + ((u >> 16) & 1u)) >> 16;   // RNE
    return (unsigned short)r;
}
static __device__ __forceinline__ float bf2f(unsigned short v) {
    return __uint_as_float(((unsigned)v) << 16);
}

// Zero stats + stat8 + gcur (59 KB). Own kernel: runtime fill costs ~40 us.
__global__ __launch_bounds__(256) void prezero_k(i32x4* __restrict__ zws) {
    int i = blockIdx.x * 256 + threadIdx.x;
    if (i < ZERO_V4) zws[i] = (i32x4){0, 0, 0, 0};
}

// Fused cast + partition (block-role split).
// Blocks [0,256): partition -> globally bucket-sorted claims via one padded
//   global atomic per (block,bucket); gcur[b*16] ends as bucket edge count.
// Blocks [256,...): cast feature to column-sliced bf16 fb + W to wb.
__global__ __launch_bounds__(256) void castpart_k(const float* __restrict__ feat,
                                                  const float* __restrict__ W,
                                                  u16x8* __restrict__ fb,
                                                  u16x8* __restrict__ wb,
                                                  const int* __restrict__ src,
                                                  const int* __restrict__ dst,
                                                  int* __restrict__ gcur,
                                                  unsigned* __restrict__ claims) {
    __shared__ unsigned pk[PART_CHUNK];      // 12,500 B
    __shared__ int hist[NBUCKET];            // 3,128 B
    __shared__ int base_l[NBUCKET];          // 3,128 B
    const int t = threadIdx.x;

    if (blockIdx.x < PART_BLOCKS) {
        const int base = blockIdx.x * PART_CHUNK;

        for (int b = t; b < NBUCKET; b += 256) hist[b] = 0;
        __syncthreads();

        for (int i = t; i < PART_CHUNK; i += 256) {
            int s = __builtin_nontemporal_load(src + base + i);
            int d = __builtin_nontemporal_load(dst + base + i);
            pk[i] = ((unsigned)s << 16) | (unsigned)d;
            atomicAdd(&hist[d >> 6], 1);
        }
        __syncthreads();

        for (int b = t; b < NBUCKET; b += 256) {
            int h = hist[b];
            base_l[b] = h ? atomicAdd(gcur + b * 16, h) : 0;
            hist[b] = 0;                      // reuse as running offset
        }
        __syncthreads();

        for (int i = t; i < PART_CHUNK; i += 256) {
            unsigned u = pk[i];
            int bkt = (int)(u & 0xffffu) >> 6;
            int k = atomicAdd(&hist[bkt], 1);
            int pos = base_l[bkt] + k;
            if (pos < BCAP) claims[bkt * BCAP + pos] = u;
        }
    } else {
        int i = (blockIdx.x - PART_BLOCKS) * 256 + t;
        if (i < FEAT_V8) {
            // job i -> slice q, node n, octet oc; fb[i] IS the sliced address
            int q  = i / SLICE_V8;                // 0..3
            int r  = i - q * SLICE_V8;
            int n  = r >> 2, oc = r & 3;
            const f32x4* fp = reinterpret_cast<const f32x4*>(feat + n * D + q * 32 + oc * 8);
            f32x4 x0 = __builtin_nontemporal_load(fp);
            f32x4 x1 = __builtin_nontemporal_load(fp + 1);
            u16x8 o;
            o[0] = f2bf(x0.x); o[1] = f2bf(x0.y); o[2] = f2bf(x0.z); o[3] = f2bf(x0.w);
            o[4] = f2bf(x1.x); o[5] = f2bf(x1.y); o[6] = f2bf(x1.z); o[7] = f2bf(x1.w);
            __builtin_nontemporal_store(o, fb + i);
        } else if (i < FEAT_V8 + W_V8) {
            int j = i - FEAT_V8;
            const f32x4* fp = reinterpret_cast<const f32x4*>(W) + j * 2;
            f32x4 x0 = __builtin_nontemporal_load(fp);
            f32x4 x1 = __builtin_nontemporal_load(fp + 1);
            u16x8 o;
            o[0] = f2bf(x0.x); o[1] = f2bf(x0.y); o[2] = f2bf(x0.z); o[3] = f2bf(x0.w);
            o[4] = f2bf(x1.x); o[5] = f2bf(x1.y); o[6] = f2bf(x1.z); o[7] = f2bf(x1.w);
            __builtin_nontemporal_store(o, wb + j);
        }
    }
}

// Bin + gather, column-quarter sliced. Block = (bucket b, quarter q).
// Bin: bucket's claims are contiguous -> coalesced sweeps into LDS slot lists.
// Gather: thread = (node, octet); 4 lanes of a node read the same 64 B fb
// line; fb slice (3.2 MB) stays in one XCD's L2 (q = blockIdx&3 round-robin).
// hb output is SLICED like fb -> fully coalesced contiguous write.
__global__ __launch_bounds__(256) void bingather_k(const int* __restrict__ gcur,
                                                   const unsigned* __restrict__ claims,
                                                   const u16x8* __restrict__ fb,
                                                   u16x8* __restrict__ hb) {
    __shared__ unsigned short ebl[64 * SLOTS_P];   // 6,400 B
    __shared__ int lcnt[64];
    const int t = threadIdx.x;
    const int b = blockIdx.x >> 2;
    const int q = blockIdx.x & 3;
    const u16x8* fbq = fb + (size_t)q * SLICE_V8;

    if (t < 64) lcnt[t] = 0;
    __syncthreads();

    const int n = min(gcur[b * 16], BCAP);
    const unsigned* cp = claims + b * BCAP;
    for (int i = t; i < n; i += 256) {
        unsigned u = cp[i];
        int dl = (int)(u & 63u);
        int k = atomicAdd(&lcnt[dl], 1);
        if (k < SLOTS) ebl[dl * SLOTS_P + k] = (unsigned short)(u >> 16);
    }
    __syncthreads();

    const int nl = t >> 2;               // node-local 0..63
    const int oc = t & 3;                // octet within quarter
    const int node = (b << 6) + nl;
    const int deg = lcnt[nl];
    const int nd  = min(deg, SLOTS);
    const unsigned short* slots = ebl + nl * SLOTS_P;

    float a[8];
#pragma unroll
    for (int i = 0; i < 8; ++i) a[i] = 0.f;

    int e = 0;
    for (; e + 8 <= nd; e += 8) {        // 8-edge unroll: more loads in flight
        int s0 = slots[e],     s1 = slots[e + 1];
        int s2 = slots[e + 2], s3 = slots[e + 3];
        int s4 = slots[e + 4], s5 = slots[e + 5];
        int s6 = slots[e + 6], s7 = slots[e + 7];
        u16x8 v0 = fbq[s0 * 4 + oc];
        u16x8 v1 = fbq[s1 * 4 + oc];
        u16x8 v2 = fbq[s2 * 4 + oc];
        u16x8 v3 = fbq[s3 * 4 + oc];
        u16x8 v4 = fbq[s4 * 4 + oc];
        u16x8 v5 = fbq[s5 * 4 + oc];
        u16x8 v6 = fbq[s6 * 4 + oc];
        u16x8 v7 = fbq[s7 * 4 + oc];
#pragma unroll
        for (int i = 0; i < 8; ++i)
            a[i] += ((bf2f(v0[i]) + bf2f(v1[i])) + (bf2f(v2[i]) + bf2f(v3[i]))) +
                    ((bf2f(v4[i]) + bf2f(v5[i])) + (bf2f(v6[i]) + bf2f(v7[i])));
    }
    for (; e < nd; ++e) {
        u16x8 v0 = fbq[(int)slots[e] * 4 + oc];
#pragma unroll
        for (int i = 0; i < 8; ++i) a[i] += bf2f(v0[i]);
    }

    if (node < N_NODES) {
        float inv = (deg > 0) ? 1.f / (float)deg : 0.f;
        u16x8 o;
#pragma unroll
        for (int i = 0; i < 8; ++i) o[i] = f2bf(a[i] * inv);
        hb[(size_t)q * SLICE_V8 + node * 4 + oc] = o;   // sliced: coalesced
    }
}

// MFMA GEMM: h2(bf16) = hb @ W^T + b; column stats into 8-way-sharded
// partials (contention / 8 -> no global-atomic serialization).
__global__ __launch_bounds__(256) void gemm_mfma_k(const u16x8* __restrict__ hb,
                                                   const u16x8* __restrict__ wb,
                                                   const float* __restrict__ bias,
                                                   unsigned short* __restrict__ h2,
                                                   float* __restrict__ colsum8,
                                                   float* __restrict__ colsumsq8) {
    const int wave = threadIdx.x >> 6;
    const int lane = threadIdx.x & 63;
    const int wm = wave >> 1, wn = wave & 1;
    const int l15 = lane & 15, l4 = lane >> 4;

    short8_t bf[4][4];
#pragma unroll
    for (int t = 0; t < 4; ++t) {
        const int col = wn * 64 + t * 16 + l15;
#pragma unroll
        for (int s = 0; s < 4; ++s) {
            u16x8 w = wb[col * 16 + s * 4 + l4];
            short8_t b8;
#pragma unroll
            for (int i = 0; i < 8; ++i) b8[i] = (short)w[i];
            bf[t][s] = b8;
        }
    }
    float bc[4];
#pragma unroll
    for (int t = 0; t < 4; ++t) bc[t] = bias[wn * 64 + t * 16 + l15];

    float s1[4] = {0.f, 0.f, 0.f, 0.f};
    float s2[4] = {0.f, 0.f, 0.f, 0.f};

    for (int chunk = blockIdx.x; chunk < GEMM_CHUNKS; chunk += gridDim.x) {
        const int rbase = chunk * 32 + wm * 16;
        const int arow = min(rbase + l15, N_NODES - 1);
        short8_t af[4];
#pragma unroll
        for (int s = 0; s < 4; ++s) {
            u16x8 hv8 = hb[(size_t)s * SLICE_V8 + arow * 4 + l4];
            short8_t t8;
#pragma unroll
            for (int i = 0; i < 8; ++i) t8[i] = (short)hv8[i];
            af[s] = t8;
        }

        f32x4 acc[4];
#pragma unroll
        for (int t = 0; t < 4; ++t) acc[t] = (f32x4){0.f, 0.f, 0.f, 0.f};

#pragma unroll
        for (int s = 0; s < 4; ++s)
#pragma unroll
            for (int t = 0; t < 4; ++t)
                acc[t] = __builtin_amdgcn_mfma_f32_16x16x32_bf16(af[s], bf[t][s],
                                                                 acc[t], 0, 0, 0);

        const int orow0 = rbase + l4 * 4;
#pragma unroll
        for (int t = 0; t < 4; ++t) {
            const int col = wn * 64 + t * 16 + l15;
#pragma unroll
            for (int r = 0; r < 4; ++r) {
                const int row = orow0 + r;
                if (row < N_NODES) {
                    float hv = acc[t][r] + bc[t];
                    h2[(size_t)row * D + col] = f2bf(hv);
                    s1[t] += hv;
                    s2[t] += hv * hv;
                }
            }
        }
    }

#pragma unroll
    for (int t = 0; t < 4; ++t) {
        s1[t] += __shfl_xor(s1[t], 16); s1[t] += __shfl_xor(s1[t], 32);
        s2[t] += __shfl_xor(s2[t], 16); s2[t] += __shfl_xor(s2[t], 32);
    }
    if (lane < 16) {
        const int sh = (blockIdx.x & 7) * 128;
#pragma unroll
        for (int t = 0; t < 4; ++t) {
            int col = wn * 64 + t * 16 + lane;
            atomicAdd(colsum8 + sh + col, s1[t]);
            atomicAdd(colsumsq8 + sh + col, s2[t]);
        }
    }
}

// Fold the 8 sharded partials into final colsum/colsumsq. 1 block, 256 thr.
__global__ __launch_bounds__(256) void statreduce_k(const float* __restrict__ colsum8,
                                                    const float* __restrict__ colsumsq8,
                                                    float* __restrict__ colsum,
                                                    float* __restrict__ colsumsq) {
    int t = threadIdx.x;
    const float* src = (t < 128) ? colsum8 : colsumsq8;
    float* dst = (t < 128) ? colsum : colsumsq;
    int c = t & 127;
    float s = 0.f;
#pragma unroll
    for (int k = 0; k < 8; ++k) s += src[k * 128 + c];
    dst[c] = s;
}

// out = feature + relu((h2 - mu) * rstd * gamma + beta). h2 is bf16 (16 B per
// 8 cols); feat/out are f32 (2 x float4 per thread).
__global__ __launch_bounds__(256) void epilogue_k(const u16x8* __restrict__ h2v,
                                                  const float* __restrict__ feat,
                                                  const float* __restrict__ colsum,
                                                  const float* __restrict__ colsumsq,
                                                  const float* __restrict__ gamma,
                                                  const float* __restrict__ beta,
                                                  float* __restrict__ out) {
    int idx = blockIdx.x * 256 + threadIdx.x;      // octet index, 800,000 total
    if (idx >= FEAT_V8) return;
    const int colb = (idx * 8) & 127;
    const float inv_n = 1.0f / N_NODES;

    u16x8 hv8 = h2v[idx];
    const float4* fp = reinterpret_cast<const float4*>(feat) + idx * 2;
    float4 fv0 = fp[0], fv1 = fp[1];
    float4 o0, o1;
#pragma unroll
    for (int i = 0; i < 8; ++i) {
        int c = colb + i;
        float mu  = colsum[c] * inv_n;
        float var = colsumsq[c] * inv_n - mu * mu;
        float a   = gamma[c] * rsqrtf(var + BN_EPS);
        float bb  = beta[c] - mu * a;
        float hv  = bf2f(hv8[i]);
        float fv  = (i < 4) ? (&fv0.x)[i] : (&fv1.x)[i - 4];
        float ov  = fv + fmaxf(hv * a + bb, 0.f);
        if (i < 4) (&o0.x)[i] = ov; else (&o1.x)[i - 4] = ov;
    }
    float4* op = reinterpret_cast<float4*>(out) + idx * 2;
    op[0] = o0;
    op[1] = o1;
}

extern "C" void kernel_launch(void* const* d_in, const int* in_sizes, int n_in,
                              void* d_out, int out_size, void* d_ws, size_t ws_size,
                              hipStream_t stream) {
    const float* feature = (const float*)d_in[0];
    const float* W       = (const float*)d_in[1];
    const float* b       = (const float*)d_in[2];
    const float* gamma   = (const float*)d_in[3];
    const float* beta    = (const float*)d_in[4];
    const int*   src     = (const int*)d_in[5];
    const int*   dst     = (const int*)d_in[6];
    float* out = (float*)d_out;

    char* ws = (char*)d_ws;
    float*          colsum    = (float*)(ws + WS_STAT_OFF);
    float*          colsumsq  = colsum + 128;
    float*          colsum8   = (float*)(ws + WS_STAT8_OFF);
    float*          colsumsq8 = colsum8 + 1024;
    int*            gcur      = (int*)(ws + WS_GCUR_OFF);
    u16x8*          wb        = (u16x8*)(ws + WS_WB_OFF);
    unsigned*       claims    = (unsigned*)(ws + WS_CLAIM_OFF);
    u16x8*          hb        = (u16x8*)(ws + WS_HB_OFF);
    unsigned short* h2        = (unsigned short*)(ws + WS_H2_OFF);
    u16x8*          fb        = (u16x8*)(ws + WS_FB_OFF);

    prezero_k<<<15, 256, 0, stream>>>((i32x4*)ws);
    castpart_k<<<PART_BLOCKS + CAST_BLOCKS, 256, 0, stream>>>(
        feature, W, fb, wb, src, dst, gcur, claims);
    bingather_k<<<NBUCKET * 4, 256, 0, stream>>>(gcur, claims, fb, hb);
    gemm_mfma_k<<<GEMM_GRID, 256, 0, stream>>>(hb, wb, b, h2, colsum8, colsumsq8);
    statreduce_k<<<1, 256, 0, stream>>>(colsum8, colsumsq8, colsum, colsumsq);
    epilogue_k<<<(FEAT_V8 + 255) / 256, 256, 0, stream>>>(
        (u16x8*)h2, feature, colsum, colsumsq, gamma, beta, out);
}

// Round 21
// 89.236 us; speedup vs baseline: 1.5956x; 1.0139x over previous
//
#include <hip/hip_runtime.h>
#include <cstddef>
#include <cstdint>

#define N_NODES 50000
#define N_EDGES 800000
#define D 128
#define BN_EPS 1e-5f

// Radix binning: bucket = dst >> 6 (64 nodes/bucket)
#define NBUCKET 782                  // 782*64 = 50048 >= 50000
#define BCAP 1536                    // per-bucket claim capacity (mean 1023 + 16 sigma)
#define PART_BLOCKS 256
#define PART_CHUNK 3125              // 256 * 3125 = 800000 exact
#define SLOTS 48                     // slots per node (Poisson(16): P(>=49) ~ 1e-11)
#define SLOTS_P 50                   // LDS slot stride (25 coprime 32 -> conflict-free)
#define GEMM_CHUNKS 1563             // ceil(50000/32)
#define GEMM_GRID   512
#define FEAT_V8     (N_NODES * D / 8)   // 800,000 octet jobs
#define SLICE_V8    (N_NODES * 4)       // 200,000 octets per column-quarter slice
#define W_V8        (D * D / 8)         // 2,048
#define CAST_BLOCKS ((FEAT_V8 + W_V8 + 255) / 256)   // 3133
#define ZERO_V4     3704                // int4s covering stats+stat8+gcur (59,264 B)

typedef __attribute__((ext_vector_type(8))) short short8_t;        // 8 x bf16 (mfma operand)
typedef __attribute__((ext_vector_type(8))) unsigned short u16x8;  // 8 x u16 storage
typedef __attribute__((ext_vector_type(4))) float f32x4;
typedef __attribute__((ext_vector_type(4))) int i32x4;

// ---------------- ws layout (bytes; ws = 256 MiB) ----------------
// stats      : 2 x float[128]     @ 0           (1,024)   [unused, kept for layout]
// stat8      : 2 x float[8][128]  @ 1,024       (8,192)   [sharded partials]
// gcur       : int[782*16] padded @ 9,216       (50,048)
// wb (bf16 W): u16[16384]         @ 59,264      (32,768)
// claims     : u32[782*1536]      @ 92,032      (4,804,608)  [bucket-sorted]
// hb sliced  : u16[4][50000*32]   @ 4,896,640   (12,800,000) [bf16 agg, k-sliced]
// h2 (bf16 h): u16[50000*128]     @ 17,696,640  (12,800,000) [row-major]
// fb sliced  : u16[4][50000*32]   @ 30,496,640  (12,800,000)
#define WS_STAT_OFF    0
#define WS_STAT8_OFF   1024
#define WS_GCUR_OFF    9216
#define WS_WB_OFF      59264
#define WS_CLAIM_OFF   92032
#define WS_HB_OFF      4896640
#define WS_H2_OFF      17696640
#define WS_FB_OFF      30496640

static __device__ __forceinline__ unsigned short f2bf(float x) {
    unsigned u = __float_as_uint(x);
    unsigned r = (u + 0x7fffu + ((u >> 16) & 1u)) >> 16;   // RNE
    return (unsigned short)r;
}
static __device__ __forceinline__ float bf2f(unsigned short v) {
    return __uint_as_float(((unsigned)v) << 16);
}

// Zero stat8 + gcur (59 KB). Own kernel: runtime fill costs ~40 us.
__global__ __launch_bounds__(256) void prezero_k(i32x4* __restrict__ zws) {
    int i = blockIdx.x * 256 + threadIdx.x;
    if (i < ZERO_V4) zws[i] = (i32x4){0, 0, 0, 0};
}

// Fused cast + partition (block-role split).
// Blocks [0,256): partition -> globally bucket-sorted claims via one padded
//   global atomic per (block,bucket); gcur[b*16] ends as bucket edge count.
// Blocks [256,...): cast feature to column-sliced bf16 fb + W to wb.
__global__ __launch_bounds__(256) void castpart_k(const float* __restrict__ feat,
                                                  const float* __restrict__ W,
                                                  u16x8* __restrict__ fb,
                                                  u16x8* __restrict__ wb,
                                                  const int* __restrict__ src,
                                                  const int* __restrict__ dst,
                                                  int* __restrict__ gcur,
                                                  unsigned* __restrict__ claims) {
    __shared__ unsigned pk[PART_CHUNK];      // 12,500 B
    __shared__ int hist[NBUCKET];            // 3,128 B
    __shared__ int base_l[NBUCKET];          // 3,128 B
    const int t = threadIdx.x;

    if (blockIdx.x < PART_BLOCKS) {
        const int base = blockIdx.x * PART_CHUNK;

        for (int b = t; b < NBUCKET; b += 256) hist[b] = 0;
        __syncthreads();

        for (int i = t; i < PART_CHUNK; i += 256) {
            int s = __builtin_nontemporal_load(src + base + i);
            int d = __builtin_nontemporal_load(dst + base + i);
            pk[i] = ((unsigned)s << 16) | (unsigned)d;
            atomicAdd(&hist[d >> 6], 1);
        }
        __syncthreads();

        for (int b = t; b < NBUCKET; b += 256) {
            int h = hist[b];
            base_l[b] = h ? atomicAdd(gcur + b * 16, h) : 0;
            hist[b] = 0;                      // reuse as running offset
        }
        __syncthreads();

        for (int i = t; i < PART_CHUNK; i += 256) {
            unsigned u = pk[i];
            int bkt = (int)(u & 0xffffu) >> 6;
            int k = atomicAdd(&hist[bkt], 1);
            int pos = base_l[bkt] + k;
            if (pos < BCAP) claims[bkt * BCAP + pos] = u;
        }
    } else {
        int i = (blockIdx.x - PART_BLOCKS) * 256 + t;
        if (i < FEAT_V8) {
            // job i -> slice q, node n, octet oc; fb[i] IS the sliced address
            int q  = i / SLICE_V8;                // 0..3
            int r  = i - q * SLICE_V8;
            int n  = r >> 2, oc = r & 3;
            const f32x4* fp = reinterpret_cast<const f32x4*>(feat + n * D + q * 32 + oc * 8);
            f32x4 x0 = __builtin_nontemporal_load(fp);
            f32x4 x1 = __builtin_nontemporal_load(fp + 1);
            u16x8 o;
            o[0] = f2bf(x0.x); o[1] = f2bf(x0.y); o[2] = f2bf(x0.z); o[3] = f2bf(x0.w);
            o[4] = f2bf(x1.x); o[5] = f2bf(x1.y); o[6] = f2bf(x1.z); o[7] = f2bf(x1.w);
            __builtin_nontemporal_store(o, fb + i);
        } else if (i < FEAT_V8 + W_V8) {
            int j = i - FEAT_V8;
            const f32x4* fp = reinterpret_cast<const f32x4*>(W) + j * 2;
            f32x4 x0 = __builtin_nontemporal_load(fp);
            f32x4 x1 = __builtin_nontemporal_load(fp + 1);
            u16x8 o;
            o[0] = f2bf(x0.x); o[1] = f2bf(x0.y); o[2] = f2bf(x0.z); o[3] = f2bf(x0.w);
            o[4] = f2bf(x1.x); o[5] = f2bf(x1.y); o[6] = f2bf(x1.z); o[7] = f2bf(x1.w);
            __builtin_nontemporal_store(o, wb + j);
        }
    }
}

// Bin + gather, column-quarter sliced. Block = (bucket b, quarter q).
// Bin: bucket's claims are contiguous -> coalesced sweeps into LDS slot lists.
// Gather: thread = (node, octet); 4 lanes of a node read the same 64 B fb
// line; fb slice (3.2 MB) stays in one XCD's L2 (q = blockIdx&3 round-robin).
// hb output is SLICED like fb -> fully coalesced contiguous write.
__global__ __launch_bounds__(256) void bingather_k(const int* __restrict__ gcur,
                                                   const unsigned* __restrict__ claims,
                                                   const u16x8* __restrict__ fb,
                                                   u16x8* __restrict__ hb) {
    __shared__ unsigned short ebl[64 * SLOTS_P];   // 6,400 B
    __shared__ int lcnt[64];
    const int t = threadIdx.x;
    const int b = blockIdx.x >> 2;
    const int q = blockIdx.x & 3;
    const u16x8* fbq = fb + (size_t)q * SLICE_V8;

    if (t < 64) lcnt[t] = 0;
    __syncthreads();

    const int n = min(gcur[b * 16], BCAP);
    const unsigned* cp = claims + b * BCAP;
    for (int i = t; i < n; i += 256) {
        unsigned u = cp[i];
        int dl = (int)(u & 63u);
        int k = atomicAdd(&lcnt[dl], 1);
        if (k < SLOTS) ebl[dl * SLOTS_P + k] = (unsigned short)(u >> 16);
    }
    __syncthreads();

    const int nl = t >> 2;               // node-local 0..63
    const int oc = t & 3;                // octet within quarter
    const int node = (b << 6) + nl;
    const int deg = lcnt[nl];
    const int nd  = min(deg, SLOTS);
    const unsigned short* slots = ebl + nl * SLOTS_P;

    float a[8];
#pragma unroll
    for (int i = 0; i < 8; ++i) a[i] = 0.f;

    int e = 0;
    for (; e + 8 <= nd; e += 8) {        // 8-edge unroll: more loads in flight
        int s0 = slots[e],     s1 = slots[e + 1];
        int s2 = slots[e + 2], s3 = slots[e + 3];
        int s4 = slots[e + 4], s5 = slots[e + 5];
        int s6 = slots[e + 6], s7 = slots[e + 7];
        u16x8 v0 = fbq[s0 * 4 + oc];
        u16x8 v1 = fbq[s1 * 4 + oc];
        u16x8 v2 = fbq[s2 * 4 + oc];
        u16x8 v3 = fbq[s3 * 4 + oc];
        u16x8 v4 = fbq[s4 * 4 + oc];
        u16x8 v5 = fbq[s5 * 4 + oc];
        u16x8 v6 = fbq[s6 * 4 + oc];
        u16x8 v7 = fbq[s7 * 4 + oc];
#pragma unroll
        for (int i = 0; i < 8; ++i)
            a[i] += ((bf2f(v0[i]) + bf2f(v1[i])) + (bf2f(v2[i]) + bf2f(v3[i]))) +
                    ((bf2f(v4[i]) + bf2f(v5[i])) + (bf2f(v6[i]) + bf2f(v7[i])));
    }
    for (; e < nd; ++e) {
        u16x8 v0 = fbq[(int)slots[e] * 4 + oc];
#pragma unroll
        for (int i = 0; i < 8; ++i) a[i] += bf2f(v0[i]);
    }

    if (node < N_NODES) {
        float inv = (deg > 0) ? 1.f / (float)deg : 0.f;
        u16x8 o;
#pragma unroll
        for (int i = 0; i < 8; ++i) o[i] = f2bf(a[i] * inv);
        hb[(size_t)q * SLICE_V8 + node * 4 + oc] = o;   // sliced: coalesced
    }
}

// MFMA GEMM: h2(bf16) = hb @ W^T + b; column stats into 8-way-sharded
// partials. wm=0/1 waves pre-combined in LDS -> half the global atomics.
__global__ __launch_bounds__(256) void gemm_mfma_k(const u16x8* __restrict__ hb,
                                                   const u16x8* __restrict__ wb,
                                                   const float* __restrict__ bias,
                                                   unsigned short* __restrict__ h2,
                                                   float* __restrict__ colsum8,
                                                   float* __restrict__ colsumsq8) {
    __shared__ float sred[2][128];       // [stat][col] combine buffer
    const int wave = threadIdx.x >> 6;
    const int lane = threadIdx.x & 63;
    const int wm = wave >> 1, wn = wave & 1;
    const int l15 = lane & 15, l4 = lane >> 4;

    short8_t bf[4][4];
#pragma unroll
    for (int t = 0; t < 4; ++t) {
        const int col = wn * 64 + t * 16 + l15;
#pragma unroll
        for (int s = 0; s < 4; ++s) {
            u16x8 w = wb[col * 16 + s * 4 + l4];
            short8_t b8;
#pragma unroll
            for (int i = 0; i < 8; ++i) b8[i] = (short)w[i];
            bf[t][s] = b8;
        }
    }
    float bc[4];
#pragma unroll
    for (int t = 0; t < 4; ++t) bc[t] = bias[wn * 64 + t * 16 + l15];

    float s1[4] = {0.f, 0.f, 0.f, 0.f};
    float s2[4] = {0.f, 0.f, 0.f, 0.f};

    for (int chunk = blockIdx.x; chunk < GEMM_CHUNKS; chunk += gridDim.x) {
        const int rbase = chunk * 32 + wm * 16;
        const int arow = min(rbase + l15, N_NODES - 1);
        short8_t af[4];
#pragma unroll
        for (int s = 0; s < 4; ++s) {
            u16x8 hv8 = hb[(size_t)s * SLICE_V8 + arow * 4 + l4];
            short8_t t8;
#pragma unroll
            for (int i = 0; i < 8; ++i) t8[i] = (short)hv8[i];
            af[s] = t8;
        }

        f32x4 acc[4];
#pragma unroll
        for (int t = 0; t < 4; ++t) acc[t] = (f32x4){0.f, 0.f, 0.f, 0.f};

#pragma unroll
        for (int s = 0; s < 4; ++s)
#pragma unroll
            for (int t = 0; t < 4; ++t)
                acc[t] = __builtin_amdgcn_mfma_f32_16x16x32_bf16(af[s], bf[t][s],
                                                                 acc[t], 0, 0, 0);

        const int orow0 = rbase + l4 * 4;
#pragma unroll
        for (int t = 0; t < 4; ++t) {
            const int col = wn * 64 + t * 16 + l15;
#pragma unroll
            for (int r = 0; r < 4; ++r) {
                const int row = orow0 + r;
                if (row < N_NODES) {
                    float hv = acc[t][r] + bc[t];
                    h2[(size_t)row * D + col] = f2bf(hv);
                    s1[t] += hv;
                    s2[t] += hv * hv;
                }
            }
        }
    }

#pragma unroll
    for (int t = 0; t < 4; ++t) {
        s1[t] += __shfl_xor(s1[t], 16); s1[t] += __shfl_xor(s1[t], 32);
        s2[t] += __shfl_xor(s2[t], 16); s2[t] += __shfl_xor(s2[t], 32);
    }
    // wm=0 seeds LDS, wm=1 adds, then wm=0 does the global atomics.
    if (lane < 16 && wm == 0) {
#pragma unroll
        for (int t = 0; t < 4; ++t) {
            int col = wn * 64 + t * 16 + lane;
            sred[0][col] = s1[t];
            sred[1][col] = s2[t];
        }
    }
    __syncthreads();
    if (lane < 16 && wm == 1) {
#pragma unroll
        for (int t = 0; t < 4; ++t) {
            int col = wn * 64 + t * 16 + lane;
            sred[0][col] += s1[t];
            sred[1][col] += s2[t];
        }
    }
    __syncthreads();
    if (lane < 16 && wm == 0) {
        const int sh = (blockIdx.x & 7) * 128;
#pragma unroll
        for (int t = 0; t < 4; ++t) {
            int col = wn * 64 + t * 16 + lane;
            atomicAdd(colsum8 + sh + col, sred[0][col]);
            atomicAdd(colsumsq8 + sh + col, sred[1][col]);
        }
    }
}

// out = feature + relu((h2 - mu) * rstd * gamma + beta). Stats folded from
// the 8 shards in-block (stat8 is L2-hot, 8 KB). NT on feat/out streams.
__global__ __launch_bounds__(256) void epilogue_k(const u16x8* __restrict__ h2v,
                                                  const float* __restrict__ feat,
                                                  const float* __restrict__ colsum8,
                                                  const float* __restrict__ colsumsq8,
                                                  const float* __restrict__ gamma,
                                                  const float* __restrict__ beta,
                                                  float* __restrict__ out) {
    __shared__ float av_l[128], bv_l[128];
    const int t = threadIdx.x;
    if (t < 128) {
        const float inv_n = 1.0f / N_NODES;
        float s1 = 0.f, s2 = 0.f;
#pragma unroll
        for (int k = 0; k < 8; ++k) {
            s1 += colsum8[k * 128 + t];
            s2 += colsumsq8[k * 128 + t];
        }
        float mu  = s1 * inv_n;
        float var = s2 * inv_n - mu * mu;
        float a   = gamma[t] * rsqrtf(var + BN_EPS);
        av_l[t] = a;
        bv_l[t] = beta[t] - mu * a;
    }
    __syncthreads();

    int idx = blockIdx.x * 256 + t;               // octet index, 800,000 total
    if (idx >= FEAT_V8) return;
    const int colb = (idx * 8) & 127;

    u16x8 hv8 = h2v[idx];
    const f32x4* fp = reinterpret_cast<const f32x4*>(feat) + idx * 2;
    f32x4 fv0 = __builtin_nontemporal_load(fp);
    f32x4 fv1 = __builtin_nontemporal_load(fp + 1);
    f32x4 o0, o1;
#pragma unroll
    for (int i = 0; i < 8; ++i) {
        int c = colb + i;
        float hv = bf2f(hv8[i]);
        float fv = (i < 4) ? fv0[i] : fv1[i - 4];
        float ov = fv + fmaxf(hv * av_l[c] + bv_l[c], 0.f);
        if (i < 4) o0[i] = ov; else o1[i - 4] = ov;
    }
    f32x4* op = reinterpret_cast<f32x4*>(out) + idx * 2;
    __builtin_nontemporal_store(o0, op);
    __builtin_nontemporal_store(o1, op + 1);
}

extern "C" void kernel_launch(void* const* d_in, const int* in_sizes, int n_in,
                              void* d_out, int out_size, void* d_ws, size_t ws_size,
                              hipStream_t stream) {
    const float* feature = (const float*)d_in[0];
    const float* W       = (const float*)d_in[1];
    const float* b       = (const float*)d_in[2];
    const float* gamma   = (const float*)d_in[3];
    const float* beta    = (const float*)d_in[4];
    const int*   src     = (const int*)d_in[5];
    const int*   dst     = (const int*)d_in[6];
    float* out = (float*)d_out;

    char* ws = (char*)d_ws;
    float*          colsum8   = (float*)(ws + WS_STAT8_OFF);
    float*          colsumsq8 = colsum8 + 1024;
    int*            gcur      = (int*)(ws + WS_GCUR_OFF);
    u16x8*          wb        = (u16x8*)(ws + WS_WB_OFF);
    unsigned*       claims    = (unsigned*)(ws + WS_CLAIM_OFF);
    u16x8*          hb        = (u16x8*)(ws + WS_HB_OFF);
    unsigned short* h2        = (unsigned short*)(ws + WS_H2_OFF);
    u16x8*          fb        = (u16x8*)(ws + WS_FB_OFF);

    prezero_k<<<15, 256, 0, stream>>>((i32x4*)ws);
    castpart_k<<<PART_BLOCKS + CAST_BLOCKS, 256, 0, stream>>>(
        feature, W, fb, wb, src, dst, gcur, claims);
    bingather_k<<<NBUCKET * 4, 256, 0, stream>>>(gcur, claims, fb, hb);
    gemm_mfma_k<<<GEMM_GRID, 256, 0, stream>>>(hb, wb, b, h2, colsum8, colsumsq8);
    epilogue_k<<<(FEAT_V8 + 255) / 256, 256, 0, stream>>>(
        (u16x8*)h2, feature, colsum8, colsumsq8, gamma, beta, out);
}